// Round 11
// baseline (6069.500 us; speedup 1.0000x reference)
//
#include <hip/hip_runtime.h>
#include <hip/hip_bf16.h>

#define B_ 128
#define T_ 1024
#define E_ 32
#define H_ 100
#define C_ 20
#define M_ (B_*T_)   // 131072

typedef __attribute__((ext_vector_type(8))) short bf16x8v;
typedef __attribute__((ext_vector_type(4))) float f32x4v;

static __device__ __forceinline__ short f2b(float x) {
  union { __hip_bfloat16 b; short s; } u;
  u.b = __float2bfloat16(x);
  return u.s;
}

// ---------------- embedding lookup ----------------
__global__ void embed_k(const int* __restrict__ tok, const float* __restrict__ emb,
                        float* __restrict__ x0) {
  int idx = blockIdx.x * 256 + threadIdx.x;   // over M_*E_ = 4194304
  int bt = idx >> 5;
  int e  = idx & 31;
  x0[idx] = emb[tok[bt] * E_ + e];
}

// ---------------- fp32 GEMM (kept for tiny N=20 emission matmul) ----------
__global__ __launch_bounds__(256) void gemm_nt(
    const float* __restrict__ A, const float* __restrict__ W,
    const float* __restrict__ b1, const float* __restrict__ b2,
    float* __restrict__ C, int K, int N, int ldc)
{
  const int BK = 8;
  __shared__ __align__(16) float As[BK][68];
  __shared__ __align__(16) float Ws[BK][68];
  int tid = threadIdx.x;
  size_t m0 = (size_t)blockIdx.x * 64;
  int n0 = blockIdx.y * 64;
  int ty = tid >> 4, tx = tid & 15;
  int lm = tid >> 2;
  int lk = (tid & 3) * 2;
  float acc[4][4] = {{0.f}};
  const float* Ap = A + (m0 + (size_t)lm) * K + lk;
  bool wok = (n0 + lm) < N;
  const float* Wp = wok ? (W + (size_t)(n0 + lm) * K + lk) : W;
  for (int k0 = 0; k0 < K; k0 += BK) {
    float2 av = *(const float2*)(Ap + k0);
    float2 wv = wok ? *(const float2*)(Wp + k0) : make_float2(0.f, 0.f);
    As[lk][lm] = av.x; As[lk + 1][lm] = av.y;
    Ws[lk][lm] = wv.x; Ws[lk + 1][lm] = wv.y;
    __syncthreads();
    #pragma unroll
    for (int k = 0; k < BK; ++k) {
      float4 a4 = *(const float4*)&As[k][ty * 4];
      float4 w4 = *(const float4*)&Ws[k][tx * 4];
      float ar[4] = {a4.x, a4.y, a4.z, a4.w};
      float wr[4] = {w4.x, w4.y, w4.z, w4.w};
      #pragma unroll
      for (int i = 0; i < 4; ++i)
        #pragma unroll
        for (int j = 0; j < 4; ++j)
          acc[i][j] = fmaf(ar[i], wr[j], acc[i][j]);
    }
    __syncthreads();
  }
  #pragma unroll
  for (int i = 0; i < 4; ++i) {
    size_t row = m0 + ty * 4 + i;
    #pragma unroll
    for (int j = 0; j < 4; ++j) {
      int col = n0 + tx * 4 + j;
      if (col < N) {
        float bv = (b1 ? b1[col] : 0.f) + (b2 ? b2[col] : 0.f);
        C[row * (size_t)ldc + col] = acc[i][j] + bv;
      }
    }
  }
}

// ---------------- bf16 MFMA GEMM: C[M,N] = A[M,K] @ W[N,K]^T + b1 + b2 ------
__global__ __launch_bounds__(256) void gemm_mfma(
    const float* __restrict__ A, const float* __restrict__ W,
    const float* __restrict__ b1, const float* __restrict__ b2,
    float* __restrict__ C, int K, int N, int ldc)
{
  __shared__ short as[64 * 40];   // [row][k] pad 40
  __shared__ short ws[64 * 40];   // [col][k]
  int tid = threadIdx.x, lane = tid & 63, w = tid >> 6;
  int lr = lane & 15, lq = lane >> 4;
  size_t m0 = (size_t)blockIdx.x * 64;
  int n0 = blockIdx.y * 64;
  int srow = tid >> 2;            // staging row 0..63
  int sk = (tid & 3) * 8;         // staging k offset 0,8,16,24
  bool wok = (n0 + srow) < N;
  const float* Ap = A + (m0 + srow) * (size_t)K + sk;
  const float* Wp = wok ? (W + (size_t)(n0 + srow) * K + sk) : W;
  f32x4v acc[4];
  #pragma unroll
  for (int r = 0; r < 4; ++r) acc[r] = (f32x4v){0.f, 0.f, 0.f, 0.f};
  int ksteps = (K + 31) / 32;
  for (int ks = 0; ks < ksteps; ++ks) {
    int kk = ks * 32;
    bf16x8v av, wv;
    if (kk + sk + 7 < K) {
      float4 a0 = *(const float4*)(Ap + kk);
      float4 a1 = *(const float4*)(Ap + kk + 4);
      av[0]=f2b(a0.x); av[1]=f2b(a0.y); av[2]=f2b(a0.z); av[3]=f2b(a0.w);
      av[4]=f2b(a1.x); av[5]=f2b(a1.y); av[6]=f2b(a1.z); av[7]=f2b(a1.w);
      if (wok) {
        float4 w0 = *(const float4*)(Wp + kk);
        float4 w1 = *(const float4*)(Wp + kk + 4);
        wv[0]=f2b(w0.x); wv[1]=f2b(w0.y); wv[2]=f2b(w0.z); wv[3]=f2b(w0.w);
        wv[4]=f2b(w1.x); wv[5]=f2b(w1.y); wv[6]=f2b(w1.z); wv[7]=f2b(w1.w);
      } else {
        #pragma unroll
        for (int j = 0; j < 8; ++j) wv[j] = 0;
      }
    } else {
      #pragma unroll
      for (int j = 0; j < 8; ++j) {
        int k = kk + sk + j;
        av[j] = (k < K) ? f2b(A[(m0 + srow) * (size_t)K + k]) : (short)0;
        wv[j] = (wok && k < K) ? f2b(W[(size_t)(n0 + srow) * K + k]) : (short)0;
      }
    }
    *(bf16x8v*)&as[srow * 40 + sk] = av;
    *(bf16x8v*)&ws[srow * 40 + sk] = wv;
    __syncthreads();
    bf16x8v bf = *(const bf16x8v*)&ws[(16 * w + lr) * 40 + 8 * lq];
    #pragma unroll
    for (int r = 0; r < 4; ++r) {
      bf16x8v af = *(const bf16x8v*)&as[(16 * r + lr) * 40 + 8 * lq];
      acc[r] = __builtin_amdgcn_mfma_f32_16x16x32_bf16(af, bf, acc[r], 0, 0, 0);
    }
    __syncthreads();
  }
  int col = n0 + 16 * w + lr;
  if (col < N) {
    float bv = (b1 ? b1[col] : 0.f) + (b2 ? b2[col] : 0.f);
    #pragma unroll
    for (int r = 0; r < 4; ++r)
      #pragma unroll
      for (int rg = 0; rg < 4; ++rg)
        C[(m0 + 16 * r + 4 * lq + rg) * (size_t)ldc + col] = acc[r][rg] + bv;
  }
}

// ---------------- MFMA LSTM scan, v4 -----------------
// r10 post-mortem: (1) wf spilled AGAIN (alloc 52 < demand ~110; tenth RA
// datapoint) -> pin wf in AGPRs via "+a" asm inside the loop: gfx950 MFMA
// reads B from AGPR directly, and the "a" class exits the arch-VGPR pressure
// heuristic that keeps losing. (2) hsh stride 136 shorts = bank-stride 4 ->
// 8-way conflict on af ds_read_b128 (8.6M conflicts): stride 192 + XOR
// swizzle u^((b&7)<<3). (3) 8 waves x 3-4 tiles: halves redundant af traffic.
__global__ __launch_bounds__(512, 1) void lstm_mfma(
    const float* __restrict__ xp,
    const float* __restrict__ WhhF, const float* __restrict__ WhhR,
    const float* __restrict__ h0, const float* __restrict__ c0, // [4][B][H]
    const int* __restrict__ seqlen,
    float* __restrict__ outbuf,       // [B][T][200], dir*100 offset
    int layer)
{
  int dir = blockIdx.x & 1, bg = blockIdx.x >> 1, b0 = bg * 16;
  int tid = threadIdx.x, lane = tid & 63, w = tid >> 6;   // 8 waves
  int lr = lane & 15, lq = lane >> 4;
  const float* Whh = dir ? WhhR : WhhF;
  const float* xpp = xp + (size_t)dir * B_ * T_ * 400;
  __shared__ float gsh[16 * 401];   // [batch][gate] stride 401 (odd)
  __shared__ short hsh[16 * 192];   // h bf16 [batch][k^swz], stride 192

  // wf[ti][s]: tile n = 8*ti + w (ti<3); ti==3 -> tile 24, wave 0 only
  bf16x8v wf[4][4];
  #pragma unroll
  for (int ti = 0; ti < 4; ++ti) {
    bool tv = (ti < 3) || (w == 0);
    int n = (ti == 3) ? 24 : (8 * ti + w);
    #pragma unroll
    for (int s = 0; s < 4; ++s) {
      bf16x8v f;
      #pragma unroll
      for (int j = 0; j < 8; ++j) {
        int k = 32 * s + 8 * lq + j;
        f[j] = (tv && k < 100) ? f2b(Whh[(size_t)(16 * n + lr) * 100 + k]) : (short)0;
      }
      wf[ti][s] = f;
    }
  }
  // h0 -> hsh (swizzled storage; bijective per row)
  for (int i = tid; i < 16 * 192; i += 512) {
    int b = i / 192, us = i - 192 * b;
    int u = us ^ ((b & 7) << 3);
    hsh[i] = (u < 100) ? f2b(h0[((size_t)(2 * layer + dir) * B_ + b0 + b) * 100 + u]) : (short)0;
  }
  // activation slots: idx = tid + 512r over 1600 items (b=idx/100, u=idx%100)
  float cst[4]; int slr[4], bb[4], ub[4]; bool vb[4];
  const float* xq[4];
  float xv[4][4];
  int tstep = dir ? -1 : 1;
  int t0 = dir ? (T_ - 1) : 0;
  #pragma unroll
  for (int r = 0; r < 4; ++r) {
    int idx = tid + 512 * r;
    bool v = idx < 1600;
    vb[r] = v;
    int b = v ? idx / 100 : 0;
    int u = v ? (idx - 100 * b) : 0;
    bb[r] = b; ub[r] = u;
    cst[r] = v ? c0[((size_t)(2 * layer + dir) * B_ + b0 + b) * 100 + u] : 0.f;
    slr[r] = (v && seqlen) ? seqlen[b0 + b] : T_;
    xq[r] = xpp + ((size_t)(b0 + b) * T_ + t0) * 400 + u;
    #pragma unroll
    for (int m = 0; m < 4; ++m) xv[r][m] = v ? xq[r][100 * m] : 0.f;
    xq[r] += tstep * 400;
  }
  __syncthreads();

  for (int tt = 0; tt < T_; ++tt) {
    // pin weight frags into AGPRs every iteration (no remat, no arch-VGPR
    // pressure; gfx950 MFMA consumes AGPR B-operands directly)
    #pragma unroll
    for (int ti = 0; ti < 4; ++ti)
      #pragma unroll
      for (int s = 0; s < 4; ++s)
        asm volatile("" : "+a"(wf[ti][s]));
    int t = dir ? (T_ - 1 - tt) : tt;
    // prefetch next step's xp
    float nv[4][4];
    bool pv = (tt + 1 < T_);
    #pragma unroll
    for (int r = 0; r < 4; ++r) {
      bool v = pv && vb[r];
      #pragma unroll
      for (int m = 0; m < 4; ++m) nv[r][m] = v ? xq[r][100 * m] : 0.f;
    }
    // A frags from swizzled hsh
    bf16x8v af[4];
    #pragma unroll
    for (int s = 0; s < 4; ++s)
      af[s] = *(const bf16x8v*)&hsh[lr * 192 + ((32 * s + 8 * lq) ^ ((lr & 7) << 3))];
    #pragma unroll
    for (int ti = 0; ti < 4; ++ti) {
      if (ti < 3 || w == 0) {
        int n = (ti == 3) ? 24 : (8 * ti + w);
        f32x4v acc = {0.f, 0.f, 0.f, 0.f};
        #pragma unroll
        for (int s = 0; s < 4; ++s)
          acc = __builtin_amdgcn_mfma_f32_16x16x32_bf16(af[s], wf[ti][s], acc, 0, 0, 0);
        #pragma unroll
        for (int rg = 0; rg < 4; ++rg)
          gsh[(4 * lq + rg) * 401 + 16 * n + lr] = acc[rg];
      }
    }
    __syncthreads();
    #pragma unroll
    for (int r = 0; r < 4; ++r) {
      if (vb[r]) {
        int b = bb[r], u = ub[r];
        float gi = gsh[b * 401 + u]       + xv[r][0];
        float gf = gsh[b * 401 + 100 + u] + xv[r][1];
        float gg = gsh[b * 401 + 200 + u] + xv[r][2];
        float go = gsh[b * 401 + 300 + u] + xv[r][3];
        float si = 1.f / (1.f + __expf(-gi));
        float sf = 1.f / (1.f + __expf(-gf));
        float so = 1.f / (1.f + __expf(-go));
        float tg = 1.f - 2.f / (1.f + __expf(2.f * gg));
        float cc = fmaf(sf, cst[r], si * tg);
        cst[r] = cc;
        float tc = 1.f - 2.f / (1.f + __expf(2.f * cc));
        float h = so * tc;
        hsh[b * 192 + (u ^ ((b & 7) << 3))] = f2b(h);
        outbuf[((size_t)(b0 + b) * T_ + t) * 200 + dir * 100 + u] = (t < slr[r]) ? h : 0.f;
      }
      #pragma unroll
      for (int m = 0; m < 4; ++m) xv[r][m] = nv[r][m];
      xq[r] += tstep * 400;
    }
    __syncthreads();
  }
}

// ---------------- CRF alpha (wg<B) + beta (wg>=B), one wave per batch -------
__global__ __launch_bounds__(64) void crf_k(
    const float* __restrict__ f, const float* __restrict__ g,
    float* __restrict__ alpha, float* __restrict__ beta)
{
  int wg = blockIdx.x;
  int lane = threadIdx.x;
  float gv[20], gn1[20], gn2[20], sv[20];
  #pragma unroll
  for (int q = 0; q < 20; ++q) { gv[q] = 0.f; gn1[q] = 0.f; gn2[q] = 0.f; }
  if (wg < B_) {
    int b = wg;
    const float* fp = f + (size_t)b * T_ * C_;
    const float* gp = g + (size_t)b * T_ * C_ * C_;
    float* ap = alpha + (size_t)b * T_ * C_;
    float a = 0.f;
    if (lane < C_) { a = fp[lane]; ap[lane] = a; }
    if (lane < C_) {
      #pragma unroll
      for (int q = 0; q < 20; ++q) gv[q] = gp[(size_t)1 * 400 + q * 20 + lane];
      #pragma unroll
      for (int q = 0; q < 20; ++q) gn1[q] = gp[(size_t)2 * 400 + q * 20 + lane];
    }
    for (int t = 1; t < T_; ++t) {
      if (t + 2 < T_ && lane < C_) {
        #pragma unroll
        for (int q = 0; q < 20; ++q) gn2[q] = gp[(size_t)(t + 2) * 400 + q * 20 + lane];
      }
      float ft = (lane < C_) ? fp[t * C_ + lane] : 0.f;
      float m = -3.0e38f;
      #pragma unroll
      for (int q = 0; q < 20; ++q) {
        float s = __shfl(a, q) + gv[q];
        sv[q] = s; m = fmaxf(m, s);
      }
      float sum = 0.f;
      #pragma unroll
      for (int q = 0; q < 20; ++q) sum += __expf(sv[q] - m);
      a = ft + m + __logf(sum);
      if (lane < C_) ap[(size_t)t * C_ + lane] = a;
      #pragma unroll
      for (int q = 0; q < 20; ++q) { gv[q] = gn1[q]; gn1[q] = gn2[q]; }
    }
  } else {
    int b = wg - B_;
    const float* fp = f + (size_t)b * T_ * C_;
    const float* gp = g + (size_t)b * T_ * C_ * C_;
    float* bp = beta + (size_t)b * T_ * C_;
    float bv = 0.f;
    if (lane < C_) bp[(size_t)(T_ - 1) * C_ + lane] = 0.f;
    if (lane < C_) {
      #pragma unroll
      for (int q = 0; q < 20; ++q) gv[q] = gp[(size_t)(T_ - 1) * 400 + lane * 20 + q];
      #pragma unroll
      for (int q = 0; q < 20; ++q) gn1[q] = gp[(size_t)(T_ - 2) * 400 + lane * 20 + q];
    }
    for (int t = T_ - 2; t >= 0; --t) {
      if (t >= 2 && lane < C_) {
        #pragma unroll
        for (int q = 0; q < 20; ++q) gn2[q] = gp[(size_t)(t - 1) * 400 + lane * 20 + q];
      }
      float w = ((lane < C_) ? fp[(t + 1) * C_ + lane] : 0.f) + bv;
      float m = -3.0e38f;
      #pragma unroll
      for (int q = 0; q < 20; ++q) {
        float s = gv[q] + __shfl(w, q);
        sv[q] = s; m = fmaxf(m, s);
      }
      float sum = 0.f;
      #pragma unroll
      for (int q = 0; q < 20; ++q) sum += __expf(sv[q] - m);
      bv = m + __logf(sum);
      if (lane < C_) bp[(size_t)t * C_ + lane] = bv;
      #pragma unroll
      for (int q = 0; q < 20; ++q) { gv[q] = gn1[q]; gn1[q] = gn2[q]; }
    }
  }
}

// ---------------- logZ per batch ----------------
__global__ void logz_k(const float* __restrict__ alpha, float* __restrict__ lz) {
  int b = blockIdx.x; int lane = threadIdx.x;
  float a = (lane < C_) ? alpha[((size_t)b * T_ + (T_ - 1)) * C_ + lane] : -3.0e38f;
  float m = a;
  #pragma unroll
  for (int o = 32; o > 0; o >>= 1) m = fmaxf(m, __shfl_xor(m, o));
  float e = (lane < C_) ? __expf(a - m) : 0.f;
  #pragma unroll
  for (int o = 32; o > 0; o >>= 1) e += __shfl_xor(e, o);
  if (lane == 0) lz[b] = m + __logf(e);
}

// ---------------- marginals = exp(alpha+beta-logZ) ----------------
__global__ void marg_k(const float* __restrict__ alpha, const float* __restrict__ beta,
                       const float* __restrict__ lz, float* __restrict__ out0) {
  size_t idx = (size_t)blockIdx.x * 256 + threadIdx.x;
  int b = (int)(idx / (T_ * C_));
  out0[idx] = __expf(alpha[idx] + beta[idx] - lz[b]);
}

extern "C" void kernel_launch(void* const* d_in, const int* in_sizes, int n_in,
                              void* d_out, int out_size, void* d_ws, size_t ws_size,
                              hipStream_t stream) {
  const int*   tok   = (const int*)d_in[0];
  const int*   seq   = (const int*)d_in[1];
  const float* emb   = (const float*)d_in[2];
  const float* Wih0  = (const float*)d_in[3];
  const float* Whh0  = (const float*)d_in[4];
  const float* bih0  = (const float*)d_in[5];
  const float* bhh0  = (const float*)d_in[6];
  const float* Wih0r = (const float*)d_in[7];
  const float* Whh0r = (const float*)d_in[8];
  const float* bih0r = (const float*)d_in[9];
  const float* bhh0r = (const float*)d_in[10];
  const float* Wih1  = (const float*)d_in[11];
  const float* Whh1  = (const float*)d_in[12];
  const float* bih1  = (const float*)d_in[13];
  const float* bhh1  = (const float*)d_in[14];
  const float* Wih1r = (const float*)d_in[15];
  const float* Whh1r = (const float*)d_in[16];
  const float* bih1r = (const float*)d_in[17];
  const float* bhh1r = (const float*)d_in[18];
  const float* fW    = (const float*)d_in[19];
  const float* fb    = (const float*)d_in[20];
  const float* gW    = (const float*)d_in[21];
  const float* gb    = (const float*)d_in[22];
  const float* h0    = (const float*)d_in[23];
  const float* c0    = (const float*)d_in[24];

  float* ws = (float*)d_ws;
  float* x0 = ws;                         // 4,194,304 floats
  float* xp = ws + 4194304;               // 2*B*T*400 = 104,857,600 floats
  float* x1 = ws + 109051904;             // 26,214,400 floats
  float* lz = ws + 135266304;             // 128 floats

  float* out   = (float*)d_out;
  float* f_out = out + 2621440;
  float* g_out = out + 5242880;
  float* a_out = out + 57671680;
  float* b_out = out + 60293120;

  embed_k<<<16384, 256, 0, stream>>>(tok, emb, x0);

  dim3 g400(2048, 7), g20(2048, 1);
  // layer 0 input projections (K=32), bf16 MFMA
  gemm_mfma<<<g400, 256, 0, stream>>>(x0, Wih0,  bih0,  bhh0,  xp,                    32, 400, 400);
  gemm_mfma<<<g400, 256, 0, stream>>>(x0, Wih0r, bih0r, bhh0r, xp + (size_t)52428800, 32, 400, 400);
  lstm_mfma<<<16, 512, 0, stream>>>(xp, Whh0, Whh0r, h0, c0, nullptr, x1, 0);
  // layer 1 input projections (K=200)
  gemm_mfma<<<g400, 256, 0, stream>>>(x1, Wih1,  bih1,  bhh1,  xp,                    200, 400, 400);
  gemm_mfma<<<g400, 256, 0, stream>>>(x1, Wih1r, bih1r, bhh1r, xp + (size_t)52428800, 200, 400, 400);
  lstm_mfma<<<16, 512, 0, stream>>>(xp, Whh1, Whh1r, h0, c0, seq, x1, 1);
  // emissions (fp32, tiny) + transitions (MFMA)
  gemm_nt<<<g20,  256, 0, stream>>>(x1, fW, fb, nullptr, f_out, 200, 20,  20);
  gemm_mfma<<<g400, 256, 0, stream>>>(x1, gW, gb, nullptr, g_out, 200, 400, 400);
  // CRF forward/backward
  crf_k<<<256, 64, 0, stream>>>(f_out, g_out, a_out, b_out);
  logz_k<<<128, 64, 0, stream>>>(a_out, lz);
  marg_k<<<10240, 256, 0, stream>>>(a_out, b_out, lz, out);
}

// Round 12
// 3201.310 us; speedup vs baseline: 1.8959x; 1.8959x over previous
//
#include <hip/hip_runtime.h>
#include <hip/hip_bf16.h>

#define B_ 128
#define T_ 1024
#define E_ 32
#define H_ 100
#define C_ 20
#define M_ (B_*T_)   // 131072

typedef __attribute__((ext_vector_type(8))) short bf16x8v;
typedef __attribute__((ext_vector_type(4))) float f32x4v;
typedef unsigned short u16;

static __device__ __forceinline__ short f2b(float x) {
  union { __hip_bfloat16 b; short s; } u;
  u.b = __float2bfloat16(x);
  return u.s;
}
static __device__ __forceinline__ float b2f(u16 x) {
  return __uint_as_float(((unsigned int)x) << 16);
}

// ---------------- embedding lookup ----------------
__global__ void embed_k(const int* __restrict__ tok, const float* __restrict__ emb,
                        float* __restrict__ x0) {
  int idx = blockIdx.x * 256 + threadIdx.x;   // over M_*E_ = 4194304
  int bt = idx >> 5;
  int e  = idx & 31;
  x0[idx] = emb[tok[bt] * E_ + e];
}

// ---------------- bf16 MFMA GEMM: C[M,N] = A[M,K] @ W[N,K]^T + b1 + b2 ------
// ABF: A is bf16 (else fp32, converted on stage). OBF: C written bf16.
// Fragment layout verified on-device (r9-r11 passes). BM=64 BN=64 BK=32,
// 4 waves; wave w owns col-tile w, iterates 4 row-tiles. M % 64 == 0.
template<int ABF, int OBF>
__global__ __launch_bounds__(256) void gemm_mfma_t(
    const void* __restrict__ Av, const float* __restrict__ W,
    const float* __restrict__ b1, const float* __restrict__ b2,
    void* __restrict__ Cv, int K, int N, int ldc)
{
  __shared__ short as[64 * 40];   // [row][k] pad 40
  __shared__ short ws[64 * 40];   // [col][k]
  const float* Af = (const float*)Av;
  const u16*   Ab = (const u16*)Av;
  float* Cf = (float*)Cv;
  u16*   Cb = (u16*)Cv;
  int tid = threadIdx.x, lane = tid & 63, w = tid >> 6;
  int lr = lane & 15, lq = lane >> 4;
  size_t m0 = (size_t)blockIdx.x * 64;
  int n0 = blockIdx.y * 64;
  int srow = tid >> 2;            // staging row 0..63
  int sk = (tid & 3) * 8;         // staging k offset 0,8,16,24
  bool wok = (n0 + srow) < N;
  const float* Wp = wok ? (W + (size_t)(n0 + srow) * K + sk) : W;
  size_t arow = (m0 + srow) * (size_t)K;
  f32x4v acc[4];
  #pragma unroll
  for (int r = 0; r < 4; ++r) acc[r] = (f32x4v){0.f, 0.f, 0.f, 0.f};
  int ksteps = (K + 31) / 32;
  for (int ks = 0; ks < ksteps; ++ks) {
    int kk = ks * 32;
    bf16x8v av, wv;
    if (kk + sk + 7 < K) {
      if (ABF) {
        av = *(const bf16x8v*)(Ab + arow + kk + sk);
      } else {
        float4 a0 = *(const float4*)(Af + arow + kk + sk);
        float4 a1 = *(const float4*)(Af + arow + kk + sk + 4);
        av[0]=f2b(a0.x); av[1]=f2b(a0.y); av[2]=f2b(a0.z); av[3]=f2b(a0.w);
        av[4]=f2b(a1.x); av[5]=f2b(a1.y); av[6]=f2b(a1.z); av[7]=f2b(a1.w);
      }
      if (wok) {
        float4 w0 = *(const float4*)(Wp + kk);
        float4 w1 = *(const float4*)(Wp + kk + 4);
        wv[0]=f2b(w0.x); wv[1]=f2b(w0.y); wv[2]=f2b(w0.z); wv[3]=f2b(w0.w);
        wv[4]=f2b(w1.x); wv[5]=f2b(w1.y); wv[6]=f2b(w1.z); wv[7]=f2b(w1.w);
      } else {
        #pragma unroll
        for (int j = 0; j < 8; ++j) wv[j] = 0;
      }
    } else {
      #pragma unroll
      for (int j = 0; j < 8; ++j) {
        int k = kk + sk + j;
        av[j] = (k < K) ? (ABF ? (short)Ab[arow + k] : f2b(Af[arow + k])) : (short)0;
        wv[j] = (wok && k < K) ? f2b(W[(size_t)(n0 + srow) * K + k]) : (short)0;
      }
    }
    *(bf16x8v*)&as[srow * 40 + sk] = av;
    *(bf16x8v*)&ws[srow * 40 + sk] = wv;
    __syncthreads();
    bf16x8v bf = *(const bf16x8v*)&ws[(16 * w + lr) * 40 + 8 * lq];
    #pragma unroll
    for (int r = 0; r < 4; ++r) {
      bf16x8v af = *(const bf16x8v*)&as[(16 * r + lr) * 40 + 8 * lq];
      acc[r] = __builtin_amdgcn_mfma_f32_16x16x32_bf16(af, bf, acc[r], 0, 0, 0);
    }
    __syncthreads();
  }
  int col = n0 + 16 * w + lr;
  if (col < N) {
    float bv = (b1 ? b1[col] : 0.f) + (b2 ? b2[col] : 0.f);
    #pragma unroll
    for (int r = 0; r < 4; ++r)
      #pragma unroll
      for (int rg = 0; rg < 4; ++rg) {
        size_t off = (m0 + 16 * r + 4 * lq + rg) * (size_t)ldc + col;
        float v = acc[r][rg] + bv;
        if (OBF) Cb[off] = (u16)f2b(v); else Cf[off] = v;
      }
  }
}

// Pin a float4's components into VGPRs (blocks rematerialization of the load).
#define PIN4(v) asm volatile("" : "+v"((v).x), "+v"((v).y), "+v"((v).z), "+v"((v).w))

// ---------------- LSTM scan (one WG per (batch, direction)) -----------------
// EXACT round-4 structure (measured 997-1016us, the best of 11 rounds), with
// two changes only: xp read as bf16 (halves its FETCH) and h written bf16
// (x1 consumed by bf16-MFMA GEMMs which convert anyway -> no numeric loss).
// 256 threads; tid<200 owns gate rows 2tid,2tid+1 (50 float4, PIN4'd);
// h broadcast via v_readlane; ~64KB static LDS + 24KB dynamic -> 1 WG/CU.
__global__ __launch_bounds__(256, 2) void lstm_scan(
    const u16* __restrict__ xp,
    const float* __restrict__ WhhF, const float* __restrict__ WhhR,
    const float* __restrict__ h0, const float* __restrict__ c0, // [4][B][H]
    const int* __restrict__ seqlen,   // null => no mask
    u16* __restrict__ outbuf,         // [B][T][200] bf16, dir*100 offset
    int layer)
{
  int wg = blockIdx.x; int dir = wg & 1; int b = wg >> 1;
  int tid = threadIdx.x;
  int lane = tid & 63;
  const float* Whh = dir ? WhhR : WhhF;
  const u16* xpp = xp + ((size_t)dir * B_ + b) * T_ * 400;
  const float* h0p = h0 + ((size_t)(2 * layer + dir) * B_ + b) * H_;
  const float* c0p = c0 + ((size_t)(2 * layer + dir) * B_ + b) * H_;
  __shared__ __align__(16) float hsh[104];
  __shared__ __align__(16) float gsh[400];
  __shared__ float deadpad[15744];   // occupancy cap: total static LDS ~64KB
  if (seqlen == (const int*)0x1) deadpad[tid] = 1.f;  // keep deadpad alive
  bool act = (tid < 200);
  float4 w0[25], w1[25];
  if (act) {
    const float4* p0 = (const float4*)(Whh + (size_t)(2 * tid) * H_);
    const float4* p1 = (const float4*)(Whh + (size_t)(2 * tid + 1) * H_);
    #pragma unroll
    for (int j = 0; j < 25; ++j) { w0[j] = p0[j]; w1[j] = p1[j]; }
    #pragma unroll
    for (int j = 0; j < 25; ++j) { PIN4(w0[j]); PIN4(w1[j]); }
  }
  if (tid < H_) hsh[tid] = h0p[tid];
  float c = (tid < H_) ? c0p[tid] : 0.f;
  int sl = seqlen ? seqlen[b] : T_;
  __syncthreads();
  int tstep = dir ? -1 : 1;
  int t0 = dir ? (T_ - 1) : 0;
  ushort2 xc = make_ushort2(0, 0), xn = make_ushort2(0, 0);
  if (act) {
    xc = *(const ushort2*)(xpp + (size_t)t0 * 400 + 2 * tid);
    xn = *(const ushort2*)(xpp + (size_t)(t0 + tstep) * 400 + 2 * tid);
  }
  for (int tt = 0; tt < T_; ++tt) {
    int t = t0 + tstep * tt;
    ushort2 xn2 = make_ushort2(0, 0);
    if (act && tt + 2 < T_)
      xn2 = *(const ushort2*)(xpp + (size_t)(t + 2 * tstep) * 400 + 2 * tid);
    // stage h into lanes 0..24 of every wave (tiny exec-masked fanout)
    float4 h4;
    if (lane < 25) h4 = ((const float4*)hsh)[lane];
    if (act) {
      float a0 = b2f(xc.x), a1 = b2f(xc.y);
      #pragma unroll
      for (int j = 0; j < 25; ++j) {
        float b0 = __uint_as_float(__builtin_amdgcn_readlane(__float_as_uint(h4.x), j));
        float b1 = __uint_as_float(__builtin_amdgcn_readlane(__float_as_uint(h4.y), j));
        float b2 = __uint_as_float(__builtin_amdgcn_readlane(__float_as_uint(h4.z), j));
        float b3 = __uint_as_float(__builtin_amdgcn_readlane(__float_as_uint(h4.w), j));
        a0 = fmaf(w0[j].x, b0, a0); a1 = fmaf(w1[j].x, b0, a1);
        a0 = fmaf(w0[j].y, b1, a0); a1 = fmaf(w1[j].y, b1, a1);
        a0 = fmaf(w0[j].z, b2, a0); a1 = fmaf(w1[j].z, b2, a1);
        a0 = fmaf(w0[j].w, b3, a0); a1 = fmaf(w1[j].w, b3, a1);
      }
      *(float2*)&gsh[2 * tid] = make_float2(a0, a1);
    }
    __syncthreads();
    if (tid < H_) {
      float gi = gsh[tid], gf = gsh[H_ + tid], gg = gsh[2 * H_ + tid], go = gsh[3 * H_ + tid];
      float si = 1.f / (1.f + __expf(-gi));
      float sf = 1.f / (1.f + __expf(-gf));
      float so = 1.f / (1.f + __expf(-go));
      float tg = 1.f - 2.f / (1.f + __expf(2.f * gg));
      c = fmaf(sf, c, si * tg);
      float tc = 1.f - 2.f / (1.f + __expf(2.f * c));
      float h = so * tc;
      hsh[tid] = h;
      outbuf[((size_t)b * T_ + t) * 200 + dir * H_ + tid] = (t < sl) ? (u16)f2b(h) : (u16)0;
    }
    __syncthreads();
    xc = xn; xn = xn2;
  }
}

// ---------------- CRF alpha (wg<B) + beta (wg>=B), one wave per batch -------
__global__ __launch_bounds__(64) void crf_k(
    const float* __restrict__ f, const float* __restrict__ g,
    float* __restrict__ alpha, float* __restrict__ beta)
{
  int wg = blockIdx.x;
  int lane = threadIdx.x;
  float gv[20], gn1[20], gn2[20], sv[20];
  #pragma unroll
  for (int q = 0; q < 20; ++q) { gv[q] = 0.f; gn1[q] = 0.f; gn2[q] = 0.f; }
  if (wg < B_) {
    int b = wg;
    const float* fp = f + (size_t)b * T_ * C_;
    const float* gp = g + (size_t)b * T_ * C_ * C_;
    float* ap = alpha + (size_t)b * T_ * C_;
    float a = 0.f;
    if (lane < C_) { a = fp[lane]; ap[lane] = a; }
    if (lane < C_) {
      #pragma unroll
      for (int q = 0; q < 20; ++q) gv[q] = gp[(size_t)1 * 400 + q * 20 + lane];
      #pragma unroll
      for (int q = 0; q < 20; ++q) gn1[q] = gp[(size_t)2 * 400 + q * 20 + lane];
    }
    for (int t = 1; t < T_; ++t) {
      if (t + 2 < T_ && lane < C_) {
        #pragma unroll
        for (int q = 0; q < 20; ++q) gn2[q] = gp[(size_t)(t + 2) * 400 + q * 20 + lane];
      }
      float ft = (lane < C_) ? fp[t * C_ + lane] : 0.f;
      float m = -3.0e38f;
      #pragma unroll
      for (int q = 0; q < 20; ++q) {
        float s = __shfl(a, q) + gv[q];
        sv[q] = s; m = fmaxf(m, s);
      }
      float sum = 0.f;
      #pragma unroll
      for (int q = 0; q < 20; ++q) sum += __expf(sv[q] - m);
      a = ft + m + __logf(sum);
      if (lane < C_) ap[(size_t)t * C_ + lane] = a;
      #pragma unroll
      for (int q = 0; q < 20; ++q) { gv[q] = gn1[q]; gn1[q] = gn2[q]; }
    }
  } else {
    int b = wg - B_;
    const float* fp = f + (size_t)b * T_ * C_;
    const float* gp = g + (size_t)b * T_ * C_ * C_;
    float* bp = beta + (size_t)b * T_ * C_;
    float bv = 0.f;
    if (lane < C_) bp[(size_t)(T_ - 1) * C_ + lane] = 0.f;
    if (lane < C_) {
      #pragma unroll
      for (int q = 0; q < 20; ++q) gv[q] = gp[(size_t)(T_ - 1) * 400 + lane * 20 + q];
      #pragma unroll
      for (int q = 0; q < 20; ++q) gn1[q] = gp[(size_t)(T_ - 2) * 400 + lane * 20 + q];
    }
    for (int t = T_ - 2; t >= 0; --t) {
      if (t >= 2 && lane < C_) {
        #pragma unroll
        for (int q = 0; q < 20; ++q) gn2[q] = gp[(size_t)(t - 1) * 400 + lane * 20 + q];
      }
      float w = ((lane < C_) ? fp[(t + 1) * C_ + lane] : 0.f) + bv;
      float m = -3.0e38f;
      #pragma unroll
      for (int q = 0; q < 20; ++q) {
        float s = gv[q] + __shfl(w, q);
        sv[q] = s; m = fmaxf(m, s);
      }
      float sum = 0.f;
      #pragma unroll
      for (int q = 0; q < 20; ++q) sum += __expf(sv[q] - m);
      bv = m + __logf(sum);
      if (lane < C_) bp[(size_t)t * C_ + lane] = bv;
      #pragma unroll
      for (int q = 0; q < 20; ++q) { gv[q] = gn1[q]; gn1[q] = gn2[q]; }
    }
  }
}

// ---------------- logZ per batch ----------------
__global__ void logz_k(const float* __restrict__ alpha, float* __restrict__ lz) {
  int b = blockIdx.x; int lane = threadIdx.x;
  float a = (lane < C_) ? alpha[((size_t)b * T_ + (T_ - 1)) * C_ + lane] : -3.0e38f;
  float m = a;
  #pragma unroll
  for (int o = 32; o > 0; o >>= 1) m = fmaxf(m, __shfl_xor(m, o));
  float e = (lane < C_) ? __expf(a - m) : 0.f;
  #pragma unroll
  for (int o = 32; o > 0; o >>= 1) e += __shfl_xor(e, o);
  if (lane == 0) lz[b] = m + __logf(e);
}

// ---------------- marginals = exp(alpha+beta-logZ) ----------------
__global__ void marg_k(const float* __restrict__ alpha, const float* __restrict__ beta,
                       const float* __restrict__ lz, float* __restrict__ out0) {
  size_t idx = (size_t)blockIdx.x * 256 + threadIdx.x;
  int b = (int)(idx / (T_ * C_));
  out0[idx] = __expf(alpha[idx] + beta[idx] - lz[b]);
}

extern "C" void kernel_launch(void* const* d_in, const int* in_sizes, int n_in,
                              void* d_out, int out_size, void* d_ws, size_t ws_size,
                              hipStream_t stream) {
  const int*   tok   = (const int*)d_in[0];
  const int*   seq   = (const int*)d_in[1];
  const float* emb   = (const float*)d_in[2];
  const float* Wih0  = (const float*)d_in[3];
  const float* Whh0  = (const float*)d_in[4];
  const float* bih0  = (const float*)d_in[5];
  const float* bhh0  = (const float*)d_in[6];
  const float* Wih0r = (const float*)d_in[7];
  const float* Whh0r = (const float*)d_in[8];
  const float* bih0r = (const float*)d_in[9];
  const float* bhh0r = (const float*)d_in[10];
  const float* Wih1  = (const float*)d_in[11];
  const float* Whh1  = (const float*)d_in[12];
  const float* bih1  = (const float*)d_in[13];
  const float* bhh1  = (const float*)d_in[14];
  const float* Wih1r = (const float*)d_in[15];
  const float* Whh1r = (const float*)d_in[16];
  const float* bih1r = (const float*)d_in[17];
  const float* bhh1r = (const float*)d_in[18];
  const float* fW    = (const float*)d_in[19];
  const float* fb    = (const float*)d_in[20];
  const float* gW    = (const float*)d_in[21];
  const float* gb    = (const float*)d_in[22];
  const float* h0    = (const float*)d_in[23];
  const float* c0    = (const float*)d_in[24];

  float* ws = (float*)d_ws;
  float* x0  = ws;                          // 4,194,304 floats
  u16*   xp  = (u16*)(ws + 4194304);        // 104,857,600 bf16 (52,428,800 float slots)
  u16*   x1  = (u16*)(ws + 109051904);      // 26,214,400 bf16
  float* lz  = ws + 135266304;              // 128 floats

  float* out   = (float*)d_out;
  float* f_out = out + 2621440;
  float* g_out = out + 5242880;
  float* a_out = out + 57671680;
  float* b_out = out + 60293120;

  embed_k<<<16384, 256, 0, stream>>>(tok, emb, x0);

  dim3 g400(2048, 7), g20(2048, 1);
  // layer 0 input projections (K=32): fp32 A -> bf16 xp
  gemm_mfma_t<0,1><<<g400, 256, 0, stream>>>(x0, Wih0,  bih0,  bhh0,  xp,                    32, 400, 400);
  gemm_mfma_t<0,1><<<g400, 256, 0, stream>>>(x0, Wih0r, bih0r, bhh0r, xp + (size_t)52428800, 32, 400, 400);
  lstm_scan<<<256, 256, 24576, stream>>>(xp, Whh0, Whh0r, h0, c0, nullptr, x1, 0);
  // layer 1 input projections (K=200): bf16 A -> bf16 xp
  gemm_mfma_t<1,1><<<g400, 256, 0, stream>>>(x1, Wih1,  bih1,  bhh1,  xp,                    200, 400, 400);
  gemm_mfma_t<1,1><<<g400, 256, 0, stream>>>(x1, Wih1r, bih1r, bhh1r, xp + (size_t)52428800, 200, 400, 400);
  lstm_scan<<<256, 256, 24576, stream>>>(xp, Whh1, Whh1r, h0, c0, seq, x1, 1);
  // emissions + transitions: bf16 A -> fp32 outputs
  gemm_mfma_t<1,0><<<g20,  256, 0, stream>>>(x1, fW, fb, nullptr, f_out, 200, 20,  20);
  gemm_mfma_t<1,0><<<g400, 256, 0, stream>>>(x1, gW, gb, nullptr, g_out, 200, 400, 400);
  // CRF forward/backward
  crf_k<<<256, 64, 0, stream>>>(f_out, g_out, a_out, b_out);
  logz_k<<<128, 64, 0, stream>>>(a_out, lz);
  marg_k<<<10240, 256, 0, stream>>>(a_out, b_out, lz, out);
}